// Round 1
// baseline (112.869 us; speedup 1.0000x reference)
//
#include <hip/hip_runtime.h>
#include <math.h>

#define M_BATCH 8
#define NC 1024
#define NT 512

#if defined(__has_builtin)
#if __has_builtin(__builtin_amdgcn_exp2f)
#define FAST_EXP2(x) __builtin_amdgcn_exp2f(x)
#endif
#endif
#ifndef FAST_EXP2
#define FAST_EXP2(x) exp2f(x)
#endif

// Kernel 1: per-m min/max over concat(xc, xt), write x_mid (M,2) to ws.
__global__ __launch_bounds__(256) void minmax_kernel(
        const float* __restrict__ xc, const float* __restrict__ xt,
        float* __restrict__ xmid) {
    const int m = blockIdx.x;
    const int tid = threadIdx.x;
    float mn0 = 1e30f, mx0 = -1e30f, mn1 = 1e30f, mx1 = -1e30f;
    const float* pc = xc + m * NC * 2;
    for (int i = tid; i < NC; i += 256) {
        float a = pc[i * 2 + 0], b = pc[i * 2 + 1];
        mn0 = fminf(mn0, a); mx0 = fmaxf(mx0, a);
        mn1 = fminf(mn1, b); mx1 = fmaxf(mx1, b);
    }
    const float* pt = xt + m * NT * 2;
    for (int i = tid; i < NT; i += 256) {
        float a = pt[i * 2 + 0], b = pt[i * 2 + 1];
        mn0 = fminf(mn0, a); mx0 = fmaxf(mx0, a);
        mn1 = fminf(mn1, b); mx1 = fmaxf(mx1, b);
    }
    __shared__ float s0[256], s1[256], s2[256], s3[256];
    s0[tid] = mn0; s1[tid] = mx0; s2[tid] = mn1; s3[tid] = mx1;
    __syncthreads();
    for (int s = 128; s > 0; s >>= 1) {
        if (tid < s) {
            s0[tid] = fminf(s0[tid], s0[tid + s]);
            s1[tid] = fmaxf(s1[tid], s1[tid + s]);
            s2[tid] = fminf(s2[tid], s2[tid + s]);
            s3[tid] = fmaxf(s3[tid], s3[tid + s]);
        }
        __syncthreads();
    }
    if (tid == 0) {
        xmid[m * 2 + 0] = 0.5f * (s0[0] + s1[0]);
        xmid[m * 2 + 1] = 0.5f * (s2[0] + s3[0]);
    }
}

// Kernel 2: per (m, grid-tile) block. Stage scaled context in LDS, then each
// thread owns one grid point: write x_grid and accumulate z over 1024 context
// points with w = exp2(-(dx^2+dy^2)) on pre-scaled coords.
__global__ __launch_bounds__(256) void setconv_kernel(
        const float* __restrict__ xc, const float* __restrict__ yc,
        const float* __restrict__ lsp, const float* __restrict__ xmid,
        float* __restrict__ out_grid,   // (M, ng, 2)
        float* __restrict__ out_z,      // (M, ng, 3)
        int G, int ng) {
    const int m = blockIdx.y;
    const int g = blockIdx.x * 256 + threadIdx.x;

    // lengthscale = 1e-5 + softplus(param); scale so w = exp2(-d2)
    // exp(-0.5*((dx/ls0)^2+(dy/ls1)^2)) == exp2(-((K*dx/ls0)^2+(K*dy/ls1)^2))
    // with K = sqrt(0.5*log2(e)).
    const float K = 0.84932180028801904272f;  // sqrt(0.5*1.44269504...)
    const float ls0 = 1e-5f + log1pf(expf(lsp[0]));
    const float ls1 = 1e-5f + log1pf(expf(lsp[1]));
    const float s0 = K / ls0, s1 = K / ls1;

    __shared__ float4 ctx[NC];  // (cx*s0, cy*s1, y0, y1) ; density channel == 1
    const float* pxc = xc + m * NC * 2;
    const float* pyc = yc + m * NC * 2;
    for (int i = threadIdx.x; i < NC; i += 256) {
        float cx = pxc[i * 2 + 0] * s0;
        float cy = pxc[i * 2 + 1] * s1;
        ctx[i] = make_float4(cx, cy, pyc[i * 2 + 0], pyc[i * 2 + 1]);
    }
    __syncthreads();

    if (g >= ng) return;

    const int half = (G - 1) >> 1;
    const int ix = g / G;
    const int iy = g - ix * G;
    const float mid0 = xmid[m * 2 + 0];
    const float mid1 = xmid[m * 2 + 1];
    const float gx = mid0 + (float)(ix - half) * (1.0f / 64.0f);
    const float gy = mid1 + (float)(iy - half) * (1.0f / 64.0f);

    out_grid[(size_t)(m * ng + g) * 2 + 0] = gx;
    out_grid[(size_t)(m * ng + g) * 2 + 1] = gy;

    const float gxs = gx * s0;
    const float gys = gy * s1;
    float a0 = 0.0f, a1 = 0.0f, a2 = 0.0f;
#pragma unroll 4
    for (int c = 0; c < NC; ++c) {
        float4 t = ctx[c];
        float dx = gxs - t.x;
        float dy = gys - t.y;
        float d2 = dx * dx + dy * dy;
        float w = FAST_EXP2(-d2);
        a0 += w * t.z;
        a1 += w * t.w;
        a2 += w;
    }
    float* oz = out_z + (size_t)(m * ng + g) * 3;
    oz[0] = a0; oz[1] = a1; oz[2] = a2;
}

extern "C" void kernel_launch(void* const* d_in, const int* in_sizes, int n_in,
                              void* d_out, int out_size, void* d_ws, size_t ws_size,
                              hipStream_t stream) {
    const float* xc  = (const float*)d_in[0];
    const float* yc  = (const float*)d_in[1];
    const float* xt  = (const float*)d_in[2];
    const float* lsp = (const float*)d_in[3];

    // out = x_grid (M*ng*2) ++ z_grid (M*ng*3)  =>  ng = out_size / (5*M)
    const int ng = out_size / (5 * M_BATCH);
    const int G = (int)(sqrt((double)ng) + 0.5);  // 129 for N=64

    float* xmid = (float*)d_ws;  // (M, 2)
    float* out_grid = (float*)d_out;
    float* out_z = out_grid + (size_t)M_BATCH * ng * 2;

    minmax_kernel<<<M_BATCH, 256, 0, stream>>>(xc, xt, xmid);

    dim3 grid((ng + 255) / 256, M_BATCH);
    setconv_kernel<<<grid, 256, 0, stream>>>(xc, yc, lsp, xmid, out_grid, out_z, G, ng);
}

// Round 2
// 96.049 us; speedup vs baseline: 1.1751x; 1.1751x over previous
//
#include <hip/hip_runtime.h>
#include <math.h>

#define M_BATCH 8
#define NC 1024
#define NT 512
#define NSLICE 4
#define SLICE (NC / NSLICE)   // 256

#if defined(__has_builtin)
#if __has_builtin(__builtin_amdgcn_exp2f)
#define FAST_EXP2(x) __builtin_amdgcn_exp2f(x)
#endif
#endif
#ifndef FAST_EXP2
#define FAST_EXP2(x) exp2f(x)
#endif

// One fused kernel. Block = (gtile, ctx_slice, m).
// Phase 1: redundant per-block min/max over this m's xc++xt -> x_mid.
// Phase 2: stage this block's 256 scaled ctx points in LDS.
// Phase 3: each thread owns one grid point; loop 256 ctx points;
//          atomicAdd 3 partial channels to out_z. Slice 0 writes x_grid.
__global__ __launch_bounds__(256) void setconv_fused(
        const float* __restrict__ xc, const float* __restrict__ yc,
        const float* __restrict__ xt, const float* __restrict__ lsp,
        float* __restrict__ out_grid,   // (M, ng, 2)
        float* __restrict__ out_z,      // (M, ng, 3)
        int G, int ng) {
    const int tid = threadIdx.x;
    const int m = blockIdx.z;
    const int slice = blockIdx.y;
    const int g = blockIdx.x * 256 + tid;

    __shared__ float4 smem[NC / NSLICE > 256 ? NC / NSLICE : 256];

    // ---- Phase 1: minmax over concat(xc[m], xt[m]) ----
    float mn0 = 1e30f, mx0 = -1e30f, mn1 = 1e30f, mx1 = -1e30f;
    const float2* pc = (const float2*)(xc + m * NC * 2);
    for (int i = tid; i < NC; i += 256) {
        float2 p = pc[i];
        mn0 = fminf(mn0, p.x); mx0 = fmaxf(mx0, p.x);
        mn1 = fminf(mn1, p.y); mx1 = fmaxf(mx1, p.y);
    }
    const float2* pt = (const float2*)(xt + m * NT * 2);
    for (int i = tid; i < NT; i += 256) {
        float2 p = pt[i];
        mn0 = fminf(mn0, p.x); mx0 = fmaxf(mx0, p.x);
        mn1 = fminf(mn1, p.y); mx1 = fmaxf(mx1, p.y);
    }
    smem[tid] = make_float4(mn0, mx0, mn1, mx1);
    __syncthreads();
    for (int s = 128; s > 0; s >>= 1) {
        if (tid < s) {
            float4 a = smem[tid], b = smem[tid + s];
            smem[tid] = make_float4(fminf(a.x, b.x), fmaxf(a.y, b.y),
                                    fminf(a.z, b.z), fmaxf(a.w, b.w));
        }
        __syncthreads();
    }
    float4 mm = smem[0];
    const float mid0 = 0.5f * (mm.x + mm.y);
    const float mid1 = 0.5f * (mm.z + mm.w);
    __syncthreads();   // before smem reuse

    // ---- lengthscale scaling: w = exp2(-((K*dx/ls0)^2 + (K*dy/ls1)^2)) ----
    const float K = 0.84932180028801904272f;  // sqrt(0.5 * log2(e))
    const float ls0 = 1e-5f + log1pf(expf(lsp[0]));
    const float ls1 = 1e-5f + log1pf(expf(lsp[1]));
    const float s0 = K / ls0, s1 = K / ls1;

    // ---- Phase 2: stage this slice's ctx (scaled) ----
    const int cbase = slice * SLICE;
    const float2* pxc = (const float2*)(xc + m * NC * 2);
    const float2* pyc = (const float2*)(yc + m * NC * 2);
    if (tid < SLICE) {
        float2 cx = pxc[cbase + tid];
        float2 cy = pyc[cbase + tid];
        smem[tid] = make_float4(cx.x * s0, cx.y * s1, cy.x, cy.y);
    }
    __syncthreads();

    // ---- Phase 3: accumulate ----
    if (g < ng) {
        const int half = (G - 1) >> 1;
        const int ix = g / G;
        const int iy = g - ix * G;
        const float gx = mid0 + (float)(ix - half) * (1.0f / 64.0f);
        const float gy = mid1 + (float)(iy - half) * (1.0f / 64.0f);

        if (slice == 0) {
            float2* og = (float2*)(out_grid + (size_t)(m * ng + g) * 2);
            *og = make_float2(gx, gy);
        }

        const float gxs = gx * s0;
        const float gys = gy * s1;
        float a0 = 0.0f, a1 = 0.0f, a2 = 0.0f;
#pragma unroll 8
        for (int c = 0; c < SLICE; ++c) {
            float4 t = smem[c];
            float dx = gxs - t.x;
            float dy = gys - t.y;
            float d2 = dx * dx + dy * dy;
            float w = FAST_EXP2(-d2);
            a0 += w * t.z;
            a1 += w * t.w;
            a2 += w;
        }
        float* oz = out_z + (size_t)(m * ng + g) * 3;
        __hip_atomic_fetch_add(oz + 0, a0, __ATOMIC_RELAXED, __HIP_MEMORY_SCOPE_AGENT);
        __hip_atomic_fetch_add(oz + 1, a1, __ATOMIC_RELAXED, __HIP_MEMORY_SCOPE_AGENT);
        __hip_atomic_fetch_add(oz + 2, a2, __ATOMIC_RELAXED, __HIP_MEMORY_SCOPE_AGENT);
    }
}

extern "C" void kernel_launch(void* const* d_in, const int* in_sizes, int n_in,
                              void* d_out, int out_size, void* d_ws, size_t ws_size,
                              hipStream_t stream) {
    const float* xc  = (const float*)d_in[0];
    const float* yc  = (const float*)d_in[1];
    const float* xt  = (const float*)d_in[2];
    const float* lsp = (const float*)d_in[3];

    // out = x_grid (M*ng*2) ++ z_grid (M*ng*3)  =>  ng = out_size / (5*M)
    const int ng = out_size / (5 * M_BATCH);
    const int G = (int)(sqrt((double)ng) + 0.5);  // 129 for N=64

    float* out_grid = (float*)d_out;
    float* out_z = out_grid + (size_t)M_BATCH * ng * 2;

    // zero the z region for atomic accumulation (capture-safe async memset)
    hipMemsetAsync(out_z, 0, (size_t)M_BATCH * ng * 3 * sizeof(float), stream);

    dim3 grid((ng + 255) / 256, NSLICE, M_BATCH);
    setconv_fused<<<grid, 256, 0, stream>>>(xc, yc, xt, lsp, out_grid, out_z, G, ng);
}